// Round 1
// baseline (1075.383 us; speedup 1.0000x reference)
//
#include <hip/hip_runtime.h>
#include <math.h>

#define NH 40
#define HD 128
#define QL 8
#define ML 2048
#define HID 5120
#define CHK 128
#define NCHK 16          // ML / CHK
#define KSTR 134         // K-phase LDS row stride: (134*p+d)%32 -> only 2-way conflicts (free)
#define VSTR 132         // V-phase LDS row stride: float4-aligned (132*4 % 16 == 0)

// ---------------------------------------------------------------------------
// K1 / K4: out[q][row] = sum_h A[q][h] * W[row][h]   (A is [8][5120], W row-major)
// MODE 0: W = W_pack (15360 rows) -> q part to q_ws, k/v parts scattered into caches
// MODE 1: W = W_o (5120 rows)     -> plain [8][5120] output
// One block = 256 thr = 4 waves; each wave owns 4 rows; A staged in LDS by 1024-col chunks.
// ---------------------------------------------------------------------------
template <int MODE>
__global__ __launch_bounds__(256) void gemv8(
    const float* __restrict__ A, const float* __restrict__ W,
    const int* __restrict__ ipos,
    float* __restrict__ q_ws, float* __restrict__ k_cache,
    float* __restrict__ v_cache, float* __restrict__ out)
{
  __shared__ __align__(16) float As[QL * 1024];  // 32 KB
  const int t = threadIdx.x;
  const int wv = t >> 6, ln = t & 63;
  const int row0 = blockIdx.x * 16 + wv * 4;

  float acc[4][QL];
#pragma unroll
  for (int r = 0; r < 4; ++r)
#pragma unroll
    for (int q = 0; q < QL; ++q) acc[r][q] = 0.f;

  for (int ci = 0; ci < 5; ++ci) {
    // stage A[:, ci*1024 .. +1024) into LDS, coalesced float4
#pragma unroll
    for (int i = 0; i < 8; ++i) {
      int lin = (i * 256 + t) * 4;
      int q = lin >> 10, c = lin & 1023;
      *(float4*)(As + lin) = *(const float4*)(A + q * HID + ci * 1024 + c);
    }
    __syncthreads();
#pragma unroll
    for (int r = 0; r < 4; ++r) {
      const float* wrow = W + (size_t)(row0 + r) * HID + ci * 1024;
#pragma unroll
      for (int it = 0; it < 4; ++it) {
        int c = it * 256 + ln * 4;
        float4 w4 = *(const float4*)(wrow + c);
#pragma unroll
        for (int q = 0; q < QL; ++q) {
          float4 h4 = *(const float4*)(As + q * 1024 + c);
          acc[r][q] += w4.x * h4.x + w4.y * h4.y + w4.z * h4.z + w4.w * h4.w;
        }
      }
    }
    __syncthreads();
  }

  // wave-reduce 32 partials and write
#pragma unroll
  for (int r = 0; r < 4; ++r) {
    int row = row0 + r;
#pragma unroll
    for (int q = 0; q < QL; ++q) {
      float v = acc[r][q];
#pragma unroll
      for (int off = 32; off >= 1; off >>= 1) v += __shfl_xor(v, off, 64);
      if (ln == 0) {
        if (MODE == 0) {
          if (row < HID) {                       // Q
            int h = row >> 7, d = row & 127;
            q_ws[(h * QL + q) * HD + d] = v;
          } else if (row < 2 * HID) {            // K -> cache scatter
            int rr = row - HID;
            int h = rr >> 7, d = rr & 127;
            k_cache[((size_t)h * ML + ipos[q]) * HD + d] = v;
          } else {                               // V -> cache scatter
            int rr = row - 2 * HID;
            int h = rr >> 7, d = rr & 127;
            v_cache[((size_t)h * ML + ipos[q]) * HD + d] = v;
          }
        } else {
          out[q * HID + row] = v;
        }
      }
    }
  }
}

// ---------------------------------------------------------------------------
// K2: flash-decode partials. Block = (head, chunk of 128 positions), 256 thr.
// Phase A: scores S[8][128] = q . k / sqrt(128) + mask; per-chunk m, l, e -> LDS.
// Phase B: partial acc[8][128] = e . V -> workspace.
// ---------------------------------------------------------------------------
__global__ __launch_bounds__(256) void attn_partial(
    const float* __restrict__ kc, const float* __restrict__ vc,
    const float* __restrict__ mask, const int* __restrict__ ipos,
    const float* __restrict__ q_ws, float* __restrict__ m_ws,
    float* __restrict__ l_ws, float* __restrict__ acc_ws)
{
  __shared__ __align__(16) float kv[CHK * KSTR];   // 68.6 KB (reused K then V)
  __shared__ __align__(16) float qs[QL * HD];      // 4 KB
  __shared__ __align__(16) float se[QL * 130];     // exp(scores)
  __shared__ int ips[QL];

  const int t = threadIdx.x;
  const int head = blockIdx.x / NCHK;
  const int ch = blockIdx.x % NCHK;
  const int p0 = ch * CHK;

  // q tile + input_pos
  *(float4*)(qs + t * 4) = *(const float4*)(q_ws + head * QL * HD + t * 4);
  if (t < QL) ips[t] = ipos[t];

  // stage K chunk (stride KSTR); coalesced global f4, scalar LDS stores
  {
    const float* ks = kc + ((size_t)head * ML + p0) * HD;
#pragma unroll
    for (int i = 0; i < 16; ++i) {
      int lin = (i * 256 + t) * 4;
      float4 v = *(const float4*)(ks + lin);
      int r = lin >> 7, c = lin & 127;
      float* dst = kv + r * KSTR + c;
      dst[0] = v.x; dst[1] = v.y; dst[2] = v.z; dst[3] = v.w;
    }
  }
  __syncthreads();

  const int qi = t >> 5;
  const int ln = t & 31;

  // scores for 4 positions p = ln + 32j, one qi per thread
  float sc[4] = {0.f, 0.f, 0.f, 0.f};
  {
    const float* qrow = qs + qi * HD;
#pragma unroll 4
    for (int d = 0; d < HD; d += 2) {
      float2 q2 = *(const float2*)(qrow + d);
#pragma unroll
      for (int j = 0; j < 4; ++j) {
        float2 k2 = *(const float2*)(kv + (ln + 32 * j) * KSTR + d);
        sc[j] += q2.x * k2.x + q2.y * k2.y;
      }
    }
  }
  const float rs = 0.08838834764831845f;  // 1/sqrt(128)
  const float* mrow = mask + ((size_t)head * ML + ips[qi]) * ML + p0;
#pragma unroll
  for (int j = 0; j < 4; ++j) sc[j] = sc[j] * rs + mrow[ln + 32 * j];

  // per-chunk max over 128 positions (within the 32-lane qi group)
  float mx = fmaxf(fmaxf(sc[0], sc[1]), fmaxf(sc[2], sc[3]));
#pragma unroll
  for (int off = 16; off >= 1; off >>= 1) mx = fmaxf(mx, __shfl_xor(mx, off, 32));
  float ls = 0.f;
#pragma unroll
  for (int j = 0; j < 4; ++j) {
    float e = __expf(sc[j] - mx);
    se[qi * 130 + ln + 32 * j] = e;
    ls += e;
  }
#pragma unroll
  for (int off = 16; off >= 1; off >>= 1) ls += __shfl_xor(ls, off, 32);
  if (ln == 0) {
    m_ws[(head * NCHK + ch) * QL + qi] = mx;
    l_ws[(head * NCHK + ch) * QL + qi] = ls;
  }
  __syncthreads();  // all K reads done; safe to overwrite kv

  // stage V chunk (stride VSTR, f4-aligned rows)
  {
    const float* vs = vc + ((size_t)head * ML + p0) * HD;
#pragma unroll
    for (int i = 0; i < 16; ++i) {
      int lin = (i * 256 + t) * 4;
      float4 v = *(const float4*)(vs + lin);
      int r = lin >> 7, c = lin & 127;
      float* dst = kv + r * VSTR + c;
      dst[0] = v.x; dst[1] = v.y; dst[2] = v.z; dst[3] = v.w;
    }
  }
  __syncthreads();

  // P.V: thread owns (qi, 4 consecutive d)
  const int d0 = ln * 4;
  float4 a = {0.f, 0.f, 0.f, 0.f};
  for (int p = 0; p < CHK; ++p) {
    float e = se[qi * 130 + p];
    float4 v = *(const float4*)(kv + p * VSTR + d0);
    a.x += e * v.x; a.y += e * v.y; a.z += e * v.z; a.w += e * v.w;
  }
  *(float4*)(acc_ws + (((size_t)head * NCHK + ch) * QL + qi) * HD + d0) = a;
}

// ---------------------------------------------------------------------------
// K3: combine the 16 chunk partials per (head, qi) -> attn[qi][head*128+d]
// ---------------------------------------------------------------------------
__global__ __launch_bounds__(128) void attn_combine(
    const float* __restrict__ m_ws, const float* __restrict__ l_ws,
    const float* __restrict__ acc_ws, float* __restrict__ attn)
{
  const int head = blockIdx.x >> 3, qi = blockIdx.x & 7;
  const int t = threadIdx.x;

  float M = -INFINITY;
#pragma unroll
  for (int c = 0; c < NCHK; ++c) M = fmaxf(M, m_ws[(head * NCHK + c) * QL + qi]);
  float f[NCHK];
  float L = 0.f;
#pragma unroll
  for (int c = 0; c < NCHK; ++c) {
    float e = __expf(m_ws[(head * NCHK + c) * QL + qi] - M);
    f[c] = e;
    L += l_ws[(head * NCHK + c) * QL + qi] * e;
  }
  float o = 0.f;
#pragma unroll
  for (int c = 0; c < NCHK; ++c)
    o += f[c] * acc_ws[(((size_t)head * NCHK + c) * QL + qi) * HD + t];
  attn[qi * HID + head * HD + t] = o / L;
}

// ---------------------------------------------------------------------------
extern "C" void kernel_launch(void* const* d_in, const int* in_sizes, int n_in,
                              void* d_out, int out_size, void* d_ws, size_t ws_size,
                              hipStream_t stream)
{
  const int*   ipos = (const int*)d_in[0];
  const float* hs   = (const float*)d_in[1];
  const float* mask = (const float*)d_in[2];
  const float* Wp   = (const float*)d_in[3];
  const float* Wo   = (const float*)d_in[4];
  float*       kc   = (float*)d_in[5];  // scattered in-place; harness restores pre-launch
  float*       vc   = (float*)d_in[6];
  float*       out  = (float*)d_out;

  float* ws      = (float*)d_ws;
  float* q_ws    = ws;                   // 40960 floats: q as [head][qi][d]
  float* m_ws    = q_ws + 40960;         // 5120: [head][chunk][qi]
  float* l_ws    = m_ws + 5120;          // 5120
  float* acc_ws  = l_ws + 5120;          // 655360: [head][chunk][qi][d]
  float* attn_ws = acc_ws + 655360;      // 40960: attn [qi][5120]
  // total: 747,520 floats = 2.99 MB of d_ws

  gemv8<0><<<960, 256, 0, stream>>>(hs, Wp, ipos, q_ws, kc, vc, nullptr);
  attn_partial<<<NH * NCHK, 256, 0, stream>>>(kc, vc, mask, ipos, q_ws, m_ws, l_ws, acc_ws);
  attn_combine<<<NH * QL, 128, 0, stream>>>(m_ws, l_ws, acc_ws, attn_ws);
  gemv8<1><<<320, 256, 0, stream>>>(attn_ws, Wo, nullptr, nullptr, nullptr, nullptr, out);
}